// Round 21
// baseline (100.682 us; speedup 1.0000x reference)
//
#include <hip/hip_runtime.h>
#include <hip/hip_bf16.h>

#define H_DIM 768
#define S_LEN 128
#define NT 12        // 768 / 64 K-tiles
#define MROWS 8192   // fixed row stride of the transposed granule arrays

typedef __attribute__((ext_vector_type(8))) short short8;
typedef __attribute__((ext_vector_type(4))) float f32x4;

__device__ __forceinline__ void gload_lds16(const void* g, void* l) {
  __builtin_amdgcn_global_load_lds(
      (const __attribute__((address_space(1))) unsigned int*)g,
      (__attribute__((address_space(3))) unsigned int*)l, 16, 0, 0);
}

// ---------------- K0: per-seq ballot scan -> seq-local compact index + counts ----------------
__global__ __launch_bounds__(128) void prep_kernel(
    const int* __restrict__ mask1, const int* __restrict__ mask2,
    int* __restrict__ dest, int* __restrict__ cnts) {
  const int sq = blockIdx.x;  // 0..127 (0..63 x1, 64..127 x2)
  const int* mask = (sq < 64) ? (mask1 + sq * S_LEN) : (mask2 + (sq - 64) * S_LEN);
  const int tid = threadIdx.x;
  const int lane = tid & 63, wv = tid >> 6;
  const int m = mask[tid] ? 1 : 0;
  const unsigned long long bal = __ballot(m);
  const int pre = __popcll(bal & ((1ull << lane) - 1ull));
  __shared__ int wsum[2];
  if (lane == 0) wsum[wv] = __popcll(bal);
  __syncthreads();
  const int base = (wv == 1) ? wsum[0] : 0;
  dest[sq * S_LEN + tid] = m ? (base + pre) : -1;
  if (tid == 0) cnts[sq] = wsum[0] + wsum[1];
}

// ---------------- K1: parallel offsets + granule bitmasks (zeroing in K1b) ----------------
// Npad is 256-ALIGNED now (gemm N-tile = 256).
__global__ __launch_bounds__(512) void scan_kernel(
    const int* __restrict__ cnts, int* __restrict__ off1, int* __restrict__ off2,
    unsigned* __restrict__ vbitsM, unsigned* __restrict__ vbitsN,
    int* __restrict__ dims) {
  __shared__ int so1[65], so2[65];
  const int tid = threadIdx.x;
  const int lane = tid & 63, wv = tid >> 6;
  if (tid < 128) {  // wave 0 -> side M, wave 1 -> side N
    const int* cb = (wv == 0) ? cnts : (cnts + 64);
    const int np = (cb[lane] + 15) & ~15;
    int inc = np;
#pragma unroll
    for (int o = 1; o < 64; o <<= 1) {
      const int t = __shfl_up(inc, o);
      if (lane >= o) inc += t;
    }
    int* so = wv ? so2 : so1;
    so[lane] = inc - np;
    if (lane == 63) so[64] = inc;
  }
  __syncthreads();
  const int Mtot = so1[64], Ntot = so2[64];
  if (tid == 0) {
    const int Mpad = (Mtot + 127) & ~127;
    const int Npad = (Ntot + 255) & ~255;  // 256-aligned for the N-tile
    dims[0] = Mpad; dims[1] = Npad; dims[2] = Mpad >> 7; dims[3] = Npad >> 8;
  }
  if (tid < 65) { off1[tid] = so1[tid]; off2[tid] = so2[tid]; }
  // granule valid bits (granules never straddle seqs: offsets are 16-aligned)
  unsigned bm = 0, bn = 0;
  const int r0 = tid * 16;
  if (r0 < Mtot) {
    int s = 0;
    while (so1[s + 1] <= r0) ++s;
    const int b0 = so1[s], nv = cnts[s];
#pragma unroll
    for (int k = 0; k < 16; ++k)
      if (r0 + k - b0 < nv) bm |= (1u << k);
  }
  if (r0 < Ntot) {
    int s = 0;
    while (so2[s + 1] <= r0) ++s;
    const int b0 = so2[s], nv = cnts[64 + s];
#pragma unroll
    for (int k = 0; k < 16; ++k)
      if (r0 + k - b0 < nv) bn |= (1u << k);
  }
  vbitsM[tid] = bm;
  vbitsN[tid] = bn;
}

// ---------------- K1b: zero invalid rows, one block per candidate row ----------------
__global__ __launch_bounds__(96) void zero_kernel(
    const unsigned* __restrict__ vbitsM, const unsigned* __restrict__ vbitsN,
    const int* __restrict__ dims,
    unsigned short* __restrict__ xc1, unsigned short* __restrict__ xc2) {
  const int row = blockIdx.x;
  const short8 z8 = (short8){0, 0, 0, 0, 0, 0, 0, 0};
  if (row < dims[0] && !((vbitsM[row >> 4] >> (row & 15)) & 1u))
    reinterpret_cast<short8*>(xc1 + (size_t)row * H_DIM)[threadIdx.x] = z8;
  if (row < dims[1] && !((vbitsN[row >> 4] >> (row & 15)) & 1u))
    reinterpret_cast<short8*>(xc2 + (size_t)row * H_DIM)[threadIdx.x] = z8;
}

// ---------------- K2: per-token L2 normalize -> globally compacted bf16 rows ----------------
__global__ __launch_bounds__(256) void normc_kernel(
    const float* __restrict__ x1, const float* __restrict__ x2,
    const int* __restrict__ dest, const int* __restrict__ off1,
    const int* __restrict__ off2,
    unsigned short* __restrict__ xc1, unsigned short* __restrict__ xc2) {
  const int gid = blockIdx.x;  // 0..16383
  const int sg = gid >> 7, tok = gid & 127;
  const int d = dest[sg * S_LEN + tok];
  if (d < 0) return;  // block-uniform exit for masked tokens
  const bool is1 = (gid < 8192);
  const float* row = is1 ? (x1 + (size_t)gid * H_DIM)
                         : (x2 + (size_t)(gid - 8192) * H_DIM);
  const int grow = (is1 ? off1[sg] : off2[sg - 64]) + d;
  unsigned short* orow = (is1 ? xc1 : xc2) + (size_t)grow * H_DIM;
  const int tid = threadIdx.x;
  float4 v = make_float4(0.f, 0.f, 0.f, 0.f);
  float ss = 0.f;
  if (tid < 192) {
    v = reinterpret_cast<const float4*>(row)[tid];
    ss = v.x * v.x + v.y * v.y + v.z * v.z + v.w * v.w;
  }
#pragma unroll
  for (int o = 32; o > 0; o >>= 1) ss += __shfl_down(ss, o);
  __shared__ float ws[4];
  if ((tid & 63) == 0) ws[tid >> 6] = ss;
  __syncthreads();
  const float scale = 1.0f / sqrtf(ws[0] + ws[1] + ws[2] + ws[3]);
  if (tid < 192) {
    union { ushort4 u; __hip_bfloat16 h[4]; } o;
    o.h[0] = __float2bfloat16(v.x * scale);
    o.h[1] = __float2bfloat16(v.y * scale);
    o.h[2] = __float2bfloat16(v.z * scale);
    o.h[3] = __float2bfloat16(v.w * scale);
    reinterpret_cast<ushort4*>(orow)[tid] = o.u;
  }
}

// ---------------- K3: dense GEMM, 128x256 tile (R2-proven K-loop shape) ----------------
// 512 threads / 8 waves 2x4: wave (wm,wn) owns rows wm*64..+64 of 128, cols
// wn*64..+64 of 256. Staged bytes 0.75x of the 128x128 version (fewer A/B
// re-stages). Epilogue: granule-max stores, transposed, unique writers.
__global__ __launch_bounds__(512, 4) void gemm_kernel(
    const unsigned short* __restrict__ xc1, const unsigned short* __restrict__ xc2,
    const unsigned* __restrict__ vbitsM, const unsigned* __restrict__ vbitsN,
    const int* __restrict__ dims,
    float* __restrict__ rowgranT, float* __restrict__ colgranT) {
  __shared__ __align__(16) unsigned short Al[128 * 64];  // 16 KB
  __shared__ __align__(16) unsigned short Bl[256 * 64];  // 32 KB
  const int Nt = dims[3];               // N-tiles of 256
  const int nwork = dims[2] * Nt;
  const int bid = blockIdx.x;
  if (bid >= nwork) return;
  const int mt = bid / Nt, nt = bid - mt * Nt;
  const int tid = threadIdx.x;
  const int lane = tid & 63, w = tid >> 6;
  const int wm = w >> 2, wn = w & 3;
  const int g = lane >> 4, rl = lane & 15;
  const unsigned short* A0 = xc1 + (size_t)mt * 128 * H_DIM;
  const unsigned short* B0 = xc2 + (size_t)nt * 256 * H_DIM;

  f32x4 acc[4][4];  // row = wm*64+i*16+g*4+r, col = wn*64+j*16+rl
#pragma unroll
  for (int i = 0; i < 4; ++i)
#pragma unroll
    for (int j = 0; j < 4; ++j) acc[i][j] = (f32x4){0.f, 0.f, 0.f, 0.f};

  for (int t = 0; t < NT; ++t) {
    __syncthreads();
    const int k0 = t * 64;
    // A: 1024 chunks (2/thread); B: 2048 chunks (4/thread). Linear LDS dest,
    // inverse-swizzled global source chunk (rule 21).
#pragma unroll
    for (int q = 0; q < 2; ++q) {
      const int s = q * 512 + tid;
      const int row = s >> 3;
      const int cb = (s & 7) ^ (row & 7);
      gload_lds16(A0 + (size_t)row * H_DIM + k0 + cb * 8, Al + s * 8);
    }
#pragma unroll
    for (int q = 0; q < 4; ++q) {
      const int s = q * 512 + tid;
      const int row = s >> 3;  // 0..255
      const int cb = (s & 7) ^ (row & 7);
      gload_lds16(B0 + (size_t)row * H_DIM + k0 + cb * 8, Bl + s * 8);
    }
    __syncthreads();  // drains vmcnt(0)
#pragma unroll
    for (int kf = 0; kf < 2; ++kf) {
      const int slot = (kf * 4 + g) ^ (rl & 7);
      short8 av[4], bv[4];
#pragma unroll
      for (int i = 0; i < 4; ++i)
        av[i] = *reinterpret_cast<const short8*>(
            &Al[(wm * 64 + i * 16 + rl) * 64 + slot * 8]);
#pragma unroll
      for (int j = 0; j < 4; ++j)
        bv[j] = *reinterpret_cast<const short8*>(
            &Bl[(wn * 64 + j * 16 + rl) * 64 + slot * 8]);
      __builtin_amdgcn_s_setprio(1);
#pragma unroll
      for (int i = 0; i < 4; ++i)
#pragma unroll
        for (int j = 0; j < 4; ++j)
          acc[i][j] = __builtin_amdgcn_mfma_f32_16x16x32_bf16(
              av[i], bv[j], acc[i][j], 0, 0, 0);
      __builtin_amdgcn_s_setprio(0);
    }
  }

  // ---- epilogue: granule-level masked maxes (transposed stores) ----
  unsigned bM[4], bN[4];
#pragma unroll
  for (int i = 0; i < 4; ++i) bM[i] = vbitsM[mt * 8 + wm * 4 + i];
#pragma unroll
  for (int j = 0; j < 4; ++j) bN[j] = vbitsN[nt * 16 + wn * 4 + j];

  // per-row max over each col-granule (valid-col bit per lane)
#pragma unroll
  for (int i = 0; i < 4; ++i)
#pragma unroll
    for (int j = 0; j < 4; ++j) {
      const unsigned cvb = bN[j];
#pragma unroll
      for (int r = 0; r < 4; ++r) {
        float pm = ((cvb >> rl) & 1u) ? acc[i][j][r] : -INFINITY;
#pragma unroll
        for (int o = 1; o < 16; o <<= 1) pm = fmaxf(pm, __shfl_xor(pm, o));
        if (rl == 0)
          rowgranT[(size_t)(nt * 16 + wn * 4 + j) * MROWS + mt * 128 + wm * 64 +
                   i * 16 + g * 4 + r] = pm;
      }
    }
  // per-col max over each row-granule (valid-row bit per (g,r))
#pragma unroll
  for (int i = 0; i < 4; ++i)
#pragma unroll
    for (int j = 0; j < 4; ++j) {
      const unsigned rvb = bM[i];
      float cm = -INFINITY;
#pragma unroll
      for (int r = 0; r < 4; ++r)
        if ((rvb >> (g * 4 + r)) & 1u) cm = fmaxf(cm, acc[i][j][r]);
      cm = fmaxf(cm, __shfl_xor(cm, 16));
      cm = fmaxf(cm, __shfl_xor(cm, 32));
      if (g == 0)
        colgranT[(size_t)(mt * 8 + wm * 4 + i) * MROWS + nt * 256 + wn * 64 +
                 j * 16 + rl] = cm;
    }
}

// ---------------- K4: final reduce — one block per (a,b), coalesced reads ----------------
__global__ __launch_bounds__(128) void reduce_kernel(
    const float* __restrict__ rowgranT, const float* __restrict__ colgranT,
    const int* __restrict__ cnts, const int* __restrict__ off1,
    const int* __restrict__ off2, float* __restrict__ out) {
  const int a = blockIdx.x >> 6, b = blockIdx.x & 63;
  const int n1 = cnts[a], n2 = cnts[64 + b];
  const int o1 = off1[a], o2 = off2[b];
  const int g2s = o2 >> 4, g2n = (n2 + 15) >> 4;
  const int g1s = o1 >> 4, g1n = (n1 + 15) >> 4;
  const int tid = threadIdx.x;
  float v1 = 0.f, v2 = 0.f;
  if (tid < n1) {  // lane-contiguous: consecutive tid -> consecutive rows
    float mx = -INFINITY;
    for (int q = 0; q < g2n; ++q)
      mx = fmaxf(mx, rowgranT[(size_t)(g2s + q) * MROWS + o1 + tid]);
    v1 = mx;
  }
  if (tid < n2) {
    float mx = -INFINITY;
    for (int q = 0; q < g1n; ++q)
      mx = fmaxf(mx, colgranT[(size_t)(g1s + q) * MROWS + o2 + tid]);
    v2 = mx;
  }
#pragma unroll
  for (int o = 32; o > 0; o >>= 1) {
    v1 += __shfl_down(v1, o);
    v2 += __shfl_down(v2, o);
  }
  __shared__ float s1[2], s2[2];
  if ((tid & 63) == 0) { s1[tid >> 6] = v1; s2[tid >> 6] = v2; }
  __syncthreads();
  if (tid == 0)
    out[a * 64 + b] =
        0.5f * ((s1[0] + s1[1]) / (float)n1 + (s2[0] + s2[1]) / (float)n2);
}

extern "C" void kernel_launch(void* const* d_in, const int* in_sizes, int n_in,
                              void* d_out, int out_size, void* d_ws, size_t ws_size,
                              hipStream_t stream) {
  const float* x1 = (const float*)d_in[0];
  const int* mask1 = (const int*)d_in[1];
  const float* x2 = (const float*)d_in[2];
  const int* mask2 = (const int*)d_in[3];
  float* out = (float*)d_out;

  // workspace layout (~58.8 MB)
  unsigned short* xc1 = (unsigned short*)d_ws;            // 8192*768 bf16
  unsigned short* xc2 = xc1 + (size_t)8192 * H_DIM;       // 8192*768 bf16
  float* rowgranT = (float*)(xc2 + (size_t)8192 * H_DIM); // [512][8192] f32
  float* colgranT = rowgranT + (size_t)512 * MROWS;       // [512][8192] f32
  int* dest = (int*)(colgranT + (size_t)512 * MROWS);     // 128*128
  int* cnts = dest + 128 * S_LEN;                         // 128
  int* off1 = cnts + 128;                                 // 65
  int* off2 = off1 + 65;                                  // 65
  unsigned* vbitsM = (unsigned*)(off2 + 65);              // 512
  unsigned* vbitsN = vbitsM + 512;                        // 512
  int* dims = (int*)(vbitsN + 512);                       // 4

  prep_kernel<<<128, 128, 0, stream>>>(mask1, mask2, dest, cnts);
  scan_kernel<<<1, 512, 0, stream>>>(cnts, off1, off2, vbitsM, vbitsN, dims);
  zero_kernel<<<8192, 96, 0, stream>>>(vbitsM, vbitsN, dims, xc1, xc2);
  normc_kernel<<<16384, 256, 0, stream>>>(x1, x2, dest, off1, off2, xc1, xc2);
  gemm_kernel<<<2048, 512, 0, stream>>>(xc1, xc2, vbitsM, vbitsN, dims,
                                        rowgranT, colgranT);
  reduce_kernel<<<4096, 128, 0, stream>>>(rowgranT, colgranT, cnts, off1, off2,
                                          out);
}

// Round 22
// 93.403 us; speedup vs baseline: 1.0779x; 1.0779x over previous
//
#include <hip/hip_runtime.h>
#include <hip/hip_bf16.h>

#define H_DIM 768
#define S_LEN 128
#define NT 12        // 768 / 64 K-tiles
#define MROWS 8192   // fixed row stride of the transposed granule arrays

typedef __attribute__((ext_vector_type(8))) short short8;
typedef __attribute__((ext_vector_type(4))) float f32x4;

__device__ __forceinline__ void gload_lds16(const void* g, void* l) {
  __builtin_amdgcn_global_load_lds(
      (const __attribute__((address_space(1))) unsigned int*)g,
      (__attribute__((address_space(3))) unsigned int*)l, 16, 0, 0);
}

// ---------------- K0: per-seq ballot scan -> seq-local compact index + counts ----------------
__global__ __launch_bounds__(128) void prep_kernel(
    const int* __restrict__ mask1, const int* __restrict__ mask2,
    int* __restrict__ dest, int* __restrict__ cnts) {
  const int sq = blockIdx.x;  // 0..127 (0..63 x1, 64..127 x2)
  const int* mask = (sq < 64) ? (mask1 + sq * S_LEN) : (mask2 + (sq - 64) * S_LEN);
  const int tid = threadIdx.x;
  const int lane = tid & 63, wv = tid >> 6;
  const int m = mask[tid] ? 1 : 0;
  const unsigned long long bal = __ballot(m);
  const int pre = __popcll(bal & ((1ull << lane) - 1ull));
  __shared__ int wsum[2];
  if (lane == 0) wsum[wv] = __popcll(bal);
  __syncthreads();
  const int base = (wv == 1) ? wsum[0] : 0;
  dest[sq * S_LEN + tid] = m ? (base + pre) : -1;
  if (tid == 0) cnts[sq] = wsum[0] + wsum[1];
}

// ---------------- K1: parallel offsets + granule bitmasks (zeroing lives in K2) ----------------
__global__ __launch_bounds__(512) void scan_kernel(
    const int* __restrict__ cnts, int* __restrict__ off1, int* __restrict__ off2,
    unsigned* __restrict__ vbitsM, unsigned* __restrict__ vbitsN,
    int* __restrict__ dims) {
  __shared__ int so1[65], so2[65];
  const int tid = threadIdx.x;
  const int lane = tid & 63, wv = tid >> 6;
  if (tid < 128) {  // wave 0 -> side M, wave 1 -> side N
    const int* cb = (wv == 0) ? cnts : (cnts + 64);
    const int np = (cb[lane] + 15) & ~15;
    int inc = np;
#pragma unroll
    for (int o = 1; o < 64; o <<= 1) {
      const int t = __shfl_up(inc, o);
      if (lane >= o) inc += t;
    }
    int* so = wv ? so2 : so1;
    so[lane] = inc - np;
    if (lane == 63) so[64] = inc;
  }
  __syncthreads();
  const int Mtot = so1[64], Ntot = so2[64];
  if (tid == 0) {
    const int Mpad = (Mtot + 127) & ~127, Npad = (Ntot + 127) & ~127;
    dims[0] = Mpad; dims[1] = Npad; dims[2] = Mpad >> 7; dims[3] = Npad >> 7;
  }
  if (tid < 65) { off1[tid] = so1[tid]; off2[tid] = so2[tid]; }
  // granule valid bits (granules never straddle seqs: offsets are 16-aligned)
  unsigned bm = 0, bn = 0;
  const int r0 = tid * 16;
  if (r0 < Mtot) {
    int s = 0;
    while (so1[s + 1] <= r0) ++s;
    const int b0 = so1[s], nv = cnts[s];
#pragma unroll
    for (int k = 0; k < 16; ++k)
      if (r0 + k - b0 < nv) bm |= (1u << k);
  }
  if (r0 < Ntot) {
    int s = 0;
    while (so2[s + 1] <= r0) ++s;
    const int b0 = so2[s], nv = cnts[64 + s];
#pragma unroll
    for (int k = 0; k < 16; ++k)
      if (r0 + k - b0 < nv) bn |= (1u << k);
  }
  vbitsM[tid] = bm;
  vbitsN[tid] = bn;
}

// ---------------- K2: normalize valid tokens + zero invalid pad rows (merged) ----------------
// Blocks 0..16383: per-token L2 normalize -> compacted row (R20-proven body).
// Blocks 16384..24575: row = bid-16384; zero it in xc1/xc2 if invalid (pad).
// Disjoint row sets; both depend only on prep+scan. Saves a launch vs R20.
__global__ __launch_bounds__(256) void normzero_kernel(
    const float* __restrict__ x1, const float* __restrict__ x2,
    const int* __restrict__ dest, const int* __restrict__ off1,
    const int* __restrict__ off2,
    const unsigned* __restrict__ vbitsM, const unsigned* __restrict__ vbitsN,
    const int* __restrict__ dims,
    unsigned short* __restrict__ xc1, unsigned short* __restrict__ xc2) {
  const int gid = blockIdx.x;
  const int tid = threadIdx.x;
  if (gid >= 16384) {  // pad-row zero duty
    const int row = gid - 16384;
    if (tid < 96) {
      const short8 z8 = (short8){0, 0, 0, 0, 0, 0, 0, 0};
      if (row < dims[0] && !((vbitsM[row >> 4] >> (row & 15)) & 1u))
        reinterpret_cast<short8*>(xc1 + (size_t)row * H_DIM)[tid] = z8;
      if (row < dims[1] && !((vbitsN[row >> 4] >> (row & 15)) & 1u))
        reinterpret_cast<short8*>(xc2 + (size_t)row * H_DIM)[tid] = z8;
    }
    return;
  }
  const int sg = gid >> 7, tok = gid & 127;
  const int d = dest[sg * S_LEN + tok];
  if (d < 0) return;  // block-uniform exit for masked tokens
  const bool is1 = (gid < 8192);
  const float* row = is1 ? (x1 + (size_t)gid * H_DIM)
                         : (x2 + (size_t)(gid - 8192) * H_DIM);
  const int grow = (is1 ? off1[sg] : off2[sg - 64]) + d;
  unsigned short* orow = (is1 ? xc1 : xc2) + (size_t)grow * H_DIM;
  float4 v = make_float4(0.f, 0.f, 0.f, 0.f);
  float ss = 0.f;
  if (tid < 192) {
    v = reinterpret_cast<const float4*>(row)[tid];
    ss = v.x * v.x + v.y * v.y + v.z * v.z + v.w * v.w;
  }
#pragma unroll
  for (int o = 32; o > 0; o >>= 1) ss += __shfl_down(ss, o);
  __shared__ float ws[4];
  if ((tid & 63) == 0) ws[tid >> 6] = ss;
  __syncthreads();
  const float scale = 1.0f / sqrtf(ws[0] + ws[1] + ws[2] + ws[3]);
  if (tid < 192) {
    union { ushort4 u; __hip_bfloat16 h[4]; } o;
    o.h[0] = __float2bfloat16(v.x * scale);
    o.h[1] = __float2bfloat16(v.y * scale);
    o.h[2] = __float2bfloat16(v.z * scale);
    o.h[3] = __float2bfloat16(v.w * scale);
    reinterpret_cast<ushort4*>(orow)[tid] = o.u;
  }
}

// ---------------- K3: ONE dense GEMM over all compacted tokens (R20-proven, 60.5 us) ----------------
// 128x128 tile, 4 waves 2x2, BK=64, 4 blocks/CU — the measured-best config.
// Epilogue: transposed granule-max stores, unique writer per entry.
__global__ __launch_bounds__(256, 4) void gemm_kernel(
    const unsigned short* __restrict__ xc1, const unsigned short* __restrict__ xc2,
    const unsigned* __restrict__ vbitsM, const unsigned* __restrict__ vbitsN,
    const int* __restrict__ dims,
    float* __restrict__ rowgranT, float* __restrict__ colgranT) {
  __shared__ __align__(16) unsigned short Al[128 * 64];  // 16 KB
  __shared__ __align__(16) unsigned short Bl[128 * 64];  // 16 KB
  const int Nt = dims[3];
  const int nwork = dims[2] * Nt;
  const int bid = blockIdx.x;
  if (bid >= nwork) return;
  const int mt = bid / Nt, nt = bid - mt * Nt;
  const int tid = threadIdx.x;
  const int lane = tid & 63, w = tid >> 6;
  const int wm = w >> 1, wn = w & 1;
  const int g = lane >> 4, rl = lane & 15;
  const unsigned short* A0 = xc1 + (size_t)mt * 128 * H_DIM;
  const unsigned short* B0 = xc2 + (size_t)nt * 128 * H_DIM;

  f32x4 acc[4][4];  // row = wm*64+i*16+g*4+r, col = wn*64+j*16+rl
#pragma unroll
  for (int i = 0; i < 4; ++i)
#pragma unroll
    for (int j = 0; j < 4; ++j) acc[i][j] = (f32x4){0.f, 0.f, 0.f, 0.f};

  for (int t = 0; t < NT; ++t) {
    __syncthreads();
    const int k0 = t * 64;
    // 1024 16B-chunks per operand, 4 each per thread. Linear LDS dest,
    // inverse-swizzled global source chunk (rule 21).
#pragma unroll
    for (int q = 0; q < 4; ++q) {
      const int s = q * 256 + tid;
      const int row = s >> 3;
      const int cb = (s & 7) ^ (row & 7);
      gload_lds16(A0 + (size_t)row * H_DIM + k0 + cb * 8, Al + s * 8);
      gload_lds16(B0 + (size_t)row * H_DIM + k0 + cb * 8, Bl + s * 8);
    }
    __syncthreads();  // drains vmcnt(0)
#pragma unroll
    for (int kf = 0; kf < 2; ++kf) {
      const int slot = (kf * 4 + g) ^ (rl & 7);
      short8 av[4], bv[4];
#pragma unroll
      for (int i = 0; i < 4; ++i)
        av[i] = *reinterpret_cast<const short8*>(
            &Al[(wm * 64 + i * 16 + rl) * 64 + slot * 8]);
#pragma unroll
      for (int j = 0; j < 4; ++j)
        bv[j] = *reinterpret_cast<const short8*>(
            &Bl[(wn * 64 + j * 16 + rl) * 64 + slot * 8]);
      __builtin_amdgcn_s_setprio(1);
#pragma unroll
      for (int i = 0; i < 4; ++i)
#pragma unroll
        for (int j = 0; j < 4; ++j)
          acc[i][j] = __builtin_amdgcn_mfma_f32_16x16x32_bf16(
              av[i], bv[j], acc[i][j], 0, 0, 0);
      __builtin_amdgcn_s_setprio(0);
    }
  }

  // ---- epilogue: granule-level masked maxes (transposed stores) ----
  unsigned bM[4], bN[4];
#pragma unroll
  for (int i = 0; i < 4; ++i) bM[i] = vbitsM[mt * 8 + wm * 4 + i];
#pragma unroll
  for (int j = 0; j < 4; ++j) bN[j] = vbitsN[nt * 8 + wn * 4 + j];

  // per-row max over each col-granule (valid-col bit per lane)
#pragma unroll
  for (int i = 0; i < 4; ++i)
#pragma unroll
    for (int j = 0; j < 4; ++j) {
      const unsigned cvb = bN[j];
#pragma unroll
      for (int r = 0; r < 4; ++r) {
        float pm = ((cvb >> rl) & 1u) ? acc[i][j][r] : -INFINITY;
#pragma unroll
        for (int o = 1; o < 16; o <<= 1) pm = fmaxf(pm, __shfl_xor(pm, o));
        if (rl == 0)
          rowgranT[(size_t)(nt * 8 + wn * 4 + j) * MROWS + mt * 128 + wm * 64 +
                   i * 16 + g * 4 + r] = pm;
      }
    }
  // per-col max over each row-granule (valid-row bit per (g,r))
#pragma unroll
  for (int i = 0; i < 4; ++i)
#pragma unroll
    for (int j = 0; j < 4; ++j) {
      const unsigned rvb = bM[i];
      float cm = -INFINITY;
#pragma unroll
      for (int r = 0; r < 4; ++r)
        if ((rvb >> (g * 4 + r)) & 1u) cm = fmaxf(cm, acc[i][j][r]);
      cm = fmaxf(cm, __shfl_xor(cm, 16));
      cm = fmaxf(cm, __shfl_xor(cm, 32));
      if (g == 0)
        colgranT[(size_t)(mt * 8 + wm * 4 + i) * MROWS + nt * 128 + wn * 64 +
                 j * 16 + rl] = cm;
    }
}

// ---------------- K4: final reduce — one block per (a,b), coalesced reads ----------------
__global__ __launch_bounds__(128) void reduce_kernel(
    const float* __restrict__ rowgranT, const float* __restrict__ colgranT,
    const int* __restrict__ cnts, const int* __restrict__ off1,
    const int* __restrict__ off2, float* __restrict__ out) {
  const int a = blockIdx.x >> 6, b = blockIdx.x & 63;
  const int n1 = cnts[a], n2 = cnts[64 + b];
  const int o1 = off1[a], o2 = off2[b];
  const int g2s = o2 >> 4, g2n = (n2 + 15) >> 4;
  const int g1s = o1 >> 4, g1n = (n1 + 15) >> 4;
  const int tid = threadIdx.x;
  float v1 = 0.f, v2 = 0.f;
  if (tid < n1) {  // lane-contiguous: consecutive tid -> consecutive rows
    float mx = -INFINITY;
    for (int q = 0; q < g2n; ++q)
      mx = fmaxf(mx, rowgranT[(size_t)(g2s + q) * MROWS + o1 + tid]);
    v1 = mx;
  }
  if (tid < n2) {
    float mx = -INFINITY;
    for (int q = 0; q < g1n; ++q)
      mx = fmaxf(mx, colgranT[(size_t)(g1s + q) * MROWS + o2 + tid]);
    v2 = mx;
  }
#pragma unroll
  for (int o = 32; o > 0; o >>= 1) {
    v1 += __shfl_down(v1, o);
    v2 += __shfl_down(v2, o);
  }
  __shared__ float s1[2], s2[2];
  if ((tid & 63) == 0) { s1[tid >> 6] = v1; s2[tid >> 6] = v2; }
  __syncthreads();
  if (tid == 0)
    out[a * 64 + b] =
        0.5f * ((s1[0] + s1[1]) / (float)n1 + (s2[0] + s2[1]) / (float)n2);
}

extern "C" void kernel_launch(void* const* d_in, const int* in_sizes, int n_in,
                              void* d_out, int out_size, void* d_ws, size_t ws_size,
                              hipStream_t stream) {
  const float* x1 = (const float*)d_in[0];
  const int* mask1 = (const int*)d_in[1];
  const float* x2 = (const float*)d_in[2];
  const int* mask2 = (const int*)d_in[3];
  float* out = (float*)d_out;

  // workspace layout (~58.8 MB)
  unsigned short* xc1 = (unsigned short*)d_ws;            // 8192*768 bf16
  unsigned short* xc2 = xc1 + (size_t)8192 * H_DIM;       // 8192*768 bf16
  float* rowgranT = (float*)(xc2 + (size_t)8192 * H_DIM); // [512][8192] f32
  float* colgranT = rowgranT + (size_t)512 * MROWS;       // [512][8192] f32
  int* dest = (int*)(colgranT + (size_t)512 * MROWS);     // 128*128
  int* cnts = dest + 128 * S_LEN;                         // 128
  int* off1 = cnts + 128;                                 // 65
  int* off2 = off1 + 65;                                  // 65
  unsigned* vbitsM = (unsigned*)(off2 + 65);              // 512
  unsigned* vbitsN = vbitsM + 512;                        // 512
  int* dims = (int*)(vbitsN + 512);                       // 4

  prep_kernel<<<128, 128, 0, stream>>>(mask1, mask2, dest, cnts);
  scan_kernel<<<1, 512, 0, stream>>>(cnts, off1, off2, vbitsM, vbitsN, dims);
  normzero_kernel<<<24576, 256, 0, stream>>>(x1, x2, dest, off1, off2, vbitsM,
                                             vbitsN, dims, xc1, xc2);
  gemm_kernel<<<4096, 256, 0, stream>>>(xc1, xc2, vbitsM, vbitsN, dims,
                                        rowgranT, colgranT);
  reduce_kernel<<<4096, 128, 0, stream>>>(rowgranT, colgranT, cnts, off1, off2,
                                          out);
}